// Round 1
// baseline (555.498 us; speedup 1.0000x reference)
//
#include <hip/hip_runtime.h>
#include <stdint.h>

#define FEAT_STRIDE 16
#define PRE_NMS 6000
#define POST_NMS 300
#define NMS_TH 0.7f

static constexpr int B_ = 2, A_ = 9, H_ = 32, W_ = 32, T_ = 16;
static constexpr int LOC = H_ * W_ * T_;   // 16384
static constexpr int N_ = LOC * A_;        // 147456
static constexpr int NBIN = 65536;
static constexpr int CAP = 8192;           // candidate capacity per batch

// ---- float <-> monotonic u32 key ----
__device__ __forceinline__ uint32_t f2u(float f) {
    uint32_t b = __float_as_uint(f);
    return b ^ ((b >> 31) ? 0xFFFFFFFFu : 0x80000000u);
}
__device__ __forceinline__ float u2f(uint32_t u) {
    uint32_t b = (u >> 31) ? (u ^ 0x80000000u) : ~u;
    return __uint_as_float(b);
}

// 1) decode proposals, build sort keys, histogram top-16 key bits
__global__ void decode_kernel(const float* __restrict__ scores_map,
                              const float* __restrict__ bbox_frame,
                              const float* __restrict__ im_info,
                              const float* __restrict__ anchors,
                              float* __restrict__ boxes,
                              unsigned long long* __restrict__ keys,
                              unsigned int* __restrict__ hist) {
    int gid = blockIdx.x * blockDim.x + threadIdx.x;
    if (gid >= B_ * N_) return;
    int b = gid / N_;
    int n = gid - b * N_;
    int a = n % A_;
    int loc = n / A_;
    int k = loc % T_;
    int j = (loc / T_) % W_;
    int i = loc / (T_ * W_);

    // score = scores_map[b, A+a, i, j, k]
    float sc = scores_map[((size_t)(b * 2 * A_ + A_ + a)) * LOC + i * (W_ * T_) + j * T_ + k];

    // anchor + shift
    float ax1 = anchors[a * 6 + 0] + (float)(FEAT_STRIDE * j);
    float ay1 = anchors[a * 6 + 1] + (float)(FEAT_STRIDE * i);
    float az1 = anchors[a * 6 + 2] + (float)k;
    float ax2 = anchors[a * 6 + 3] + (float)(FEAT_STRIDE * j);
    float ay2 = anchors[a * 6 + 4] + (float)(FEAT_STRIDE * i);
    float az2 = anchors[a * 6 + 5] + (float)k;
    float aw = ax2 - ax1 + 1.0f, ah = ay2 - ay1 + 1.0f, al = az2 - az1 + 1.0f;
    float acx = ax1 + 0.5f * aw, acy = ay1 + 0.5f * ah, acz = az1 + 0.5f * al;

    // deltas: channel a*6+c of bbox_frame
    const float* dp = bbox_frame + ((size_t)(b * 6 * A_ + a * 6)) * LOC + i * (W_ * T_) + j * T_ + k;
    float d0 = dp[0 * LOC], d1 = dp[1 * LOC], d2 = dp[2 * LOC];
    float d3 = dp[3 * LOC], d4 = dp[4 * LOC], d5 = dp[5 * LOC];

    float pcx = d0 * aw + acx, pcy = d1 * ah + acy, pcz = d2 * al + acz;
    float pw = expf(d3) * aw, ph = expf(d4) * ah, pl = expf(d5) * al;

    float x1 = pcx - 0.5f * pw, y1 = pcy - 0.5f * ph, z1 = pcz - 0.5f * pl;
    float x2 = pcx + 0.5f * pw, y2 = pcy + 0.5f * ph, z2 = pcz + 0.5f * pl;

    float lx = im_info[1] - 1.0f, ly = im_info[0] - 1.0f, lz = im_info[2] - 1.0f;
    x1 = fminf(fmaxf(x1, 0.0f), lx); y1 = fminf(fmaxf(y1, 0.0f), ly); z1 = fminf(fmaxf(z1, 0.0f), lz);
    x2 = fminf(fmaxf(x2, 0.0f), lx); y2 = fminf(fmaxf(y2, 0.0f), ly); z2 = fminf(fmaxf(z2, 0.0f), lz);

    float* bp = boxes + (size_t)gid * 6;
    bp[0] = x1; bp[1] = y1; bp[2] = z1; bp[3] = x2; bp[4] = y2; bp[5] = z2;

    uint32_t u = f2u(sc);
    unsigned long long key = ((unsigned long long)u << 18) | (unsigned long long)(N_ - 1 - n);
    keys[gid] = key;
    atomicAdd(&hist[b * NBIN + (u >> 16)], 1u);
}

// 2) per batch: find histogram bin where cumulative-from-top crosses PRE_NMS
__global__ void scan_kernel(const unsigned int* __restrict__ hist,
                            unsigned int* __restrict__ thr /* [b*2]=bin, [b*2+1]=count */) {
    int bb = blockIdx.x;
    int t = threadIdx.x;                 // 1024 threads
    __shared__ unsigned int ssum[1024];
    const unsigned int* h = hist + (size_t)bb * NBIN;
    int base = t * 64;
    unsigned int s = 0;
    for (int q = 0; q < 64; ++q) s += h[base + q];
    ssum[t] = s;
    __syncthreads();
    // inclusive suffix scan (Hillis-Steele)
    for (int off = 1; off < 1024; off <<= 1) {
        unsigned int v = (t + off < 1024) ? ssum[t + off] : 0u;
        __syncthreads();
        ssum[t] += v;
        __syncthreads();
    }
    unsigned int excl = (t < 1023) ? ssum[t + 1] : 0u;
    if (excl < (unsigned)PRE_NMS && excl + s >= (unsigned)PRE_NMS) {
        unsigned int run = excl;
        for (int q = 63; q >= 0; --q) {
            run += h[base + q];
            if (run >= (unsigned)PRE_NMS) {
                thr[bb * 2 + 0] = (unsigned)(base + q);
                thr[bb * 2 + 1] = run;
                break;
            }
        }
    }
}

// 3) compact all keys whose top-16 bits >= threshold bin
__global__ void compact_kernel(const unsigned long long* __restrict__ keys,
                               const unsigned int* __restrict__ thr,
                               unsigned long long* __restrict__ cand,
                               unsigned int* __restrict__ cnt) {
    int gid = blockIdx.x * blockDim.x + threadIdx.x;
    if (gid >= B_ * N_) return;
    int b = gid / N_;
    unsigned long long key = keys[gid];
    unsigned int bin = (unsigned int)(key >> 34);
    if (bin >= thr[b * 2]) {
        unsigned int p = atomicAdd(&cnt[b], 1u);
        if (p < (unsigned)CAP) cand[(size_t)b * CAP + p] = key;
    }
}

// 4) per batch: bitonic sort (descending) of candidates in LDS, keep top PRE_NMS
__global__ void __launch_bounds__(1024) sort_kernel(unsigned long long* __restrict__ cand,
                                                    const unsigned int* __restrict__ cnt) {
    __shared__ unsigned long long sk[CAP];   // 64 KiB
    int bb = blockIdx.x, t = threadIdx.x;
    unsigned int c = cnt[bb];
    if (c > (unsigned)CAP) c = CAP;
    for (int idx = t; idx < CAP; idx += 1024)
        sk[idx] = (idx < (int)c) ? cand[(size_t)bb * CAP + idx] : 0ull;
    __syncthreads();
    for (int k = 2; k <= CAP; k <<= 1) {
        for (int j = k >> 1; j > 0; j >>= 1) {
            for (int idx = t; idx < CAP; idx += 1024) {
                int ixj = idx ^ j;
                if (ixj > idx) {
                    bool desc = ((idx & k) == 0);
                    unsigned long long a = sk[idx], bv = sk[ixj];
                    if (desc ? (a < bv) : (a > bv)) { sk[idx] = bv; sk[ixj] = a; }
                }
            }
            __syncthreads();
        }
    }
    for (int idx = t; idx < PRE_NMS; idx += 1024)
        cand[(size_t)bb * CAP + idx] = sk[idx];
}

// 5) per batch: greedy NMS (single wave), early exit at POST_NMS kept
__global__ void nms_kernel(const float* __restrict__ boxes,
                           const unsigned long long* __restrict__ cand,
                           float* __restrict__ out) {
    const int bb = blockIdx.x;
    const int lane = threadIdx.x;   // 64 threads = 1 wave
    __shared__ float kx1[POST_NMS], ky1[POST_NMS], kz1[POST_NMS];
    __shared__ float kx2[POST_NMS], ky2[POST_NMS], kz2[POST_NMS], kvol[POST_NMS];
    const int CH = 256;
    __shared__ float cb[CH][8];     // x1,y1,z1,x2,y2,z2,score,pad

    int kept = 0;
    for (int cs = 0; cs < PRE_NMS && kept < POST_NMS; cs += CH) {
        int lim = min(CH, PRE_NMS - cs);
        for (int t = lane; t < lim; t += 64) {
            unsigned long long key = cand[(size_t)bb * CAP + cs + t];
            int n = N_ - 1 - (int)(key & 0x3FFFFull);
            uint32_t u = (uint32_t)(key >> 18);
            const float* bp = boxes + ((size_t)bb * N_ + n) * 6;
            cb[t][0] = bp[0]; cb[t][1] = bp[1]; cb[t][2] = bp[2];
            cb[t][3] = bp[3]; cb[t][4] = bp[4]; cb[t][5] = bp[5];
            cb[t][6] = u2f(u);
        }
        __syncthreads();
        for (int c = 0; c < lim; ++c) {
            float x1 = cb[c][0], y1 = cb[c][1], z1 = cb[c][2];
            float x2 = cb[c][3], y2 = cb[c][4], z2 = cb[c][5];
            float scv = cb[c][6];
            float v = (x2 - x1 + 1.0f) * (y2 - y1 + 1.0f) * (z2 - z1 + 1.0f);
            bool sup = false;
            for (int t = lane; t < kept; t += 64) {
                float iw = fminf(x2, kx2[t]) - fmaxf(x1, kx1[t]) + 1.0f;
                float ih = fminf(y2, ky2[t]) - fmaxf(y1, ky1[t]) + 1.0f;
                float il = fminf(z2, kz2[t]) - fmaxf(z1, kz1[t]) + 1.0f;
                iw = fmaxf(iw, 0.0f); ih = fmaxf(ih, 0.0f); il = fmaxf(il, 0.0f);
                float inter = iw * ih * il;
                float iou = inter / (v + kvol[t] - inter);
                sup = sup || (iou > NMS_TH);
            }
            if (!__any(sup)) {
                if (lane == 0) {
                    kx1[kept] = x1; ky1[kept] = y1; kz1[kept] = z1;
                    kx2[kept] = x2; ky2[kept] = y2; kz2[kept] = z2;
                    kvol[kept] = v;
                    float* op = out + ((size_t)bb * POST_NMS + kept) * 7;
                    op[0] = scv; op[1] = x1; op[2] = y1; op[3] = z1;
                    op[4] = x2; op[5] = y2; op[6] = z2;
                }
                kept++;
                __syncthreads();   // publish kept arrays (cheap: <=300 times)
                if (kept >= POST_NMS) break;
            }
        }
        __syncthreads();
    }
    // zero-fill remaining rows
    for (int idx = kept * 7 + lane; idx < POST_NMS * 7; idx += 64)
        out[(size_t)bb * POST_NMS * 7 + idx] = 0.0f;
}

extern "C" void kernel_launch(void* const* d_in, const int* in_sizes, int n_in,
                              void* d_out, int out_size, void* d_ws, size_t ws_size,
                              hipStream_t stream) {
    const float* scores_map = (const float*)d_in[0];
    const float* bbox_frame = (const float*)d_in[1];
    const float* im_info    = (const float*)d_in[2];
    const float* anchors    = (const float*)d_in[3];
    float* out = (float*)d_out;

    // workspace layout (bytes)
    char* ws = (char*)d_ws;
    float* boxes              = (float*)(ws + 0);                      // 2*147456*6*4 = 7077888
    unsigned long long* keys  = (unsigned long long*)(ws + 7077888);   // 2*147456*8  = 2359296
    unsigned long long* cand  = (unsigned long long*)(ws + 9437184);   // 2*8192*8    = 131072
    unsigned int* hist        = (unsigned int*)(ws + 9568256);         // 2*65536*4   = 524288
    unsigned int* cnt         = (unsigned int*)(ws + 10092544);        // 8
    unsigned int* thr         = (unsigned int*)(ws + 10092552);        // 16

    hipMemsetAsync(hist, 0, 524288 + 8, stream);   // zero hist + cnt each call

    int total = B_ * N_;
    decode_kernel<<<(total + 255) / 256, 256, 0, stream>>>(scores_map, bbox_frame, im_info,
                                                           anchors, boxes, keys, hist);
    scan_kernel<<<B_, 1024, 0, stream>>>(hist, thr);
    compact_kernel<<<(total + 255) / 256, 256, 0, stream>>>(keys, thr, cand, cnt);
    sort_kernel<<<B_, 1024, 0, stream>>>(cand, cnt);
    nms_kernel<<<B_, 64, 0, stream>>>(boxes, cand, out);
}